// Round 1
// baseline (183.646 us; speedup 1.0000x reference)
//
#include <hip/hip_runtime.h>

// SelfAttention: B=4,S=4096,D=256,A=64,O=256, f32 in/out, bf16 MFMA compute.
// logits[b,s,t] = k[b,s,:]·q[b,t,:]/8, softmax over t, attn = w·v, out = attn@Wo.
// Strategy: everything in "transposed" MFMA orientation so all LDS reads are
// contiguous 16B and all stores are packed. Softmax in exp2 domain (scale
// 0.125*log2e folded into Wq).

#define SQN 4096
#define BN 4
#define DN 256
#define AN 64
#define ON 256
#define QPad 72    // 64 + 8 bf16 pad -> 144B row stride, 2-way bank conflict max
#define XPad 136
#define WPad 264

typedef short bf16x8 __attribute__((ext_vector_type(8)));
typedef float f32x4 __attribute__((ext_vector_type(4)));

__device__ __forceinline__ unsigned short f2bf(float f) {
    unsigned int u = __float_as_uint(f);
    u += 0x7fffu + ((u >> 16) & 1u);   // RNE
    return (unsigned short)(u >> 16);
}
__device__ __forceinline__ unsigned int pack2(float a, float b) {
    return (unsigned int)f2bf(a) | ((unsigned int)f2bf(b) << 16);
}
__device__ __forceinline__ float exp2_hw(float x) {
    float r; asm("v_exp_f32 %0, %1" : "=v"(r) : "v"(x)); return r;
}

// ---------------- weight transpose: W[d][a]->WT[a][d] bf16 (Wq scaled), Wo->WoT
__global__ __launch_bounds__(256) void k_wtrans(
    const float* __restrict__ Wk, const float* __restrict__ Wq,
    const float* __restrict__ Wv, const float* __restrict__ Wo,
    unsigned short* __restrict__ WT, unsigned short* __restrict__ WoT)
{
    int m = blockIdx.x, tid = threadIdx.x;
    if (m < 3) {
        const float* src = (m == 0) ? Wk : (m == 1) ? Wq : Wv;
        float scl = (m == 1) ? 0.18033688011112042f : 1.0f;  // 0.125*log2(e) folded
        unsigned short* dst = WT + m * (AN * DN);
        for (int idx = tid; idx < AN * DN; idx += 256) {
            int a = idx >> 8, d = idx & 255;
            dst[idx] = f2bf(src[d * AN + a] * scl);
        }
    } else {
        for (int idx = tid; idx < ON * AN; idx += 256) {
            int o = idx >> 6, a = idx & 63;
            WoT[idx] = f2bf(Wo[a * ON + o]);
        }
    }
}

// ---------------- projections: x[16384][256] @ W -> K,Q [s][a] bf16; V -> VT[b][a][s]
__global__ __launch_bounds__(256) void k_proj(
    const float* __restrict__ x, const unsigned short* __restrict__ WT,
    unsigned short* __restrict__ Ko, unsigned short* __restrict__ Qo,
    unsigned short* __restrict__ VTo)
{
    __shared__ unsigned short wt_lds[AN * WPad];
    __shared__ unsigned short x_lds[64 * XPad];
    const int tid = threadIdx.x;
    const int wid = tid >> 6, lane = tid & 63, g = lane >> 4, li = lane & 15;
    const int p = blockIdx.x >> 8;           // 0=K,1=Q,2=V
    const int s0 = (blockIdx.x & 255) * 64;

    {   // stage WT tile (64 x 256 bf16)
        int row = tid >> 2, seg = tid & 3;
        const uint4* src = (const uint4*)(WT + p * (AN * DN) + row * DN + seg * 64);
        uint4* dst = (uint4*)&wt_lds[row * WPad + seg * 64];
        #pragma unroll
        for (int k = 0; k < 8; ++k) dst[k] = src[k];
    }

    f32x4 acc[4] = {};
    for (int dh = 0; dh < 2; ++dh) {         // K staged in halves (LDS budget)
        __syncthreads();
        {
            int row = tid >> 2, seg = tid & 3;
            const float4* src = (const float4*)(x + (size_t)(s0 + row) * DN + dh * 128 + seg * 32);
            uint4* dst = (uint4*)&x_lds[row * XPad + seg * 32];
            #pragma unroll
            for (int k = 0; k < 4; ++k) {
                float4 v0 = src[2 * k], v1 = src[2 * k + 1];
                uint4 o;
                o.x = pack2(v0.x, v0.y); o.y = pack2(v0.z, v0.w);
                o.z = pack2(v1.x, v1.y); o.w = pack2(v1.z, v1.w);
                dst[k] = o;
            }
        }
        __syncthreads();
        #pragma unroll
        for (int dc = 0; dc < 4; ++dc) {
            bf16x8 af = *(const bf16x8*)&x_lds[(wid * 16 + li) * XPad + dc * 32 + 8 * g];
            #pragma unroll
            for (int cf = 0; cf < 4; ++cf) {
                bf16x8 bfr = *(const bf16x8*)&wt_lds[(cf * 16 + li) * WPad + dh * 128 + dc * 32 + 8 * g];
                acc[cf] = __builtin_amdgcn_mfma_f32_16x16x32_bf16(af, bfr, acc[cf], 0, 0, 0);
            }
        }
    }
    // D-frag: row(s-local)=4g+r, col(a)=cf*16+li
    if (p == 2) {
        int b = s0 >> 12;
        int sl = (s0 & 4095) + wid * 16 + 4 * g;
        #pragma unroll
        for (int cf = 0; cf < 4; ++cf) {
            int a = cf * 16 + li;
            uint2 u;
            u.x = pack2(acc[cf][0], acc[cf][1]);
            u.y = pack2(acc[cf][2], acc[cf][3]);
            *(uint2*)&VTo[(((size_t)(b * 64 + a)) << 12) + sl] = u;  // consecutive s -> packed
        }
    } else {
        unsigned short* dst = (p == 0) ? Ko : Qo;
        #pragma unroll
        for (int cf = 0; cf < 4; ++cf)
            #pragma unroll
            for (int r = 0; r < 4; ++r)
                dst[(size_t)(s0 + wid * 16 + 4 * g + r) * AN + cf * 16 + li] = f2bf(acc[cf][r]);
    }
}

// ---------------- flash attention (transposed orientation)
// Block: (b, 64 s-rows). Wave w owns rows s0+16w..+15. t-tile=64.
// S^T[t][s] = mfma(A=Q_t, B=K_s): lane(g,li) holds t=t0+16tf+4g+r, s-local=li.
// O^T[a][s] = mfma(A=VT, B=P): accumulates per-lane with softmax state in same lane.
__global__ __launch_bounds__(256) void k_attn(
    const unsigned short* __restrict__ Qg, const unsigned short* __restrict__ Kg,
    const unsigned short* __restrict__ VTg, unsigned short* __restrict__ attn)
{
    __shared__ unsigned short q_lds[64 * QPad];
    __shared__ unsigned short vt_lds[64 * QPad];
    const int tid = threadIdx.x;
    const int wid = tid >> 6, lane = tid & 63, g = lane >> 4, li = lane & 15;
    const int b = blockIdx.x >> 6;
    const int s0 = (blockIdx.x & 63) * 64;
    const size_t base = (size_t)b * SQN * AN;

    {   // stage K tile once, grab B-frags (col=li -> s=s0+16w+li, k=a)
        int row = tid >> 2, seg = tid & 3;
        const uint4* src = (const uint4*)(Kg + base + (size_t)(s0 + row) * AN + seg * 16);
        uint4* dst = (uint4*)&q_lds[row * QPad + seg * 16];
        dst[0] = src[0]; dst[1] = src[1];
    }
    __syncthreads();
    bf16x8 kfrag[2];
    kfrag[0] = *(const bf16x8*)&q_lds[(wid * 16 + li) * QPad + 8 * g];
    kfrag[1] = *(const bf16x8*)&q_lds[(wid * 16 + li) * QPad + 32 + 8 * g];

    f32x4 ot[4] = {};
    float m_run = -1e30f, l_run = 0.0f;

    for (int t0 = 0; t0 < SQN; t0 += 64) {
        __syncthreads();
        {   // stage Q[t0..][a] and VT[a][t0..]
            int row = tid >> 2, seg = tid & 3;
            const uint4* qs = (const uint4*)(Qg + base + (size_t)(t0 + row) * AN + seg * 16);
            const uint4* vs = (const uint4*)(VTg + (((size_t)(b * 64 + row)) << 12) + t0 + seg * 16);
            uint4 q0 = qs[0], q1 = qs[1], v0 = vs[0], v1 = vs[1];
            uint4* qd = (uint4*)&q_lds[row * QPad + seg * 16];
            uint4* vd = (uint4*)&vt_lds[row * QPad + seg * 16];
            qd[0] = q0; qd[1] = q1; vd[0] = v0; vd[1] = v1;
        }
        __syncthreads();

        f32x4 st[4];
        #pragma unroll
        for (int tf = 0; tf < 4; ++tf) {
            f32x4 a0 = {};
            bf16x8 qa0 = *(const bf16x8*)&q_lds[(tf * 16 + li) * QPad + 8 * g];
            bf16x8 qa1 = *(const bf16x8*)&q_lds[(tf * 16 + li) * QPad + 32 + 8 * g];
            a0 = __builtin_amdgcn_mfma_f32_16x16x32_bf16(qa0, kfrag[0], a0, 0, 0, 0);
            a0 = __builtin_amdgcn_mfma_f32_16x16x32_bf16(qa1, kfrag[1], a0, 0, 0, 0);
            st[tf] = a0;
        }

        // online softmax over t for row s=li (in-lane 16 vals + xor16/32 across g)
        float tm = -1e30f;
        #pragma unroll
        for (int tf = 0; tf < 4; ++tf)
            #pragma unroll
            for (int r = 0; r < 4; ++r) tm = fmaxf(tm, st[tf][r]);
        tm = fmaxf(tm, __shfl_xor(tm, 16));
        tm = fmaxf(tm, __shfl_xor(tm, 32));
        float m_new = fmaxf(m_run, tm);
        float alpha = exp2_hw(m_run - m_new);
        float ts = 0.0f;
        unsigned int pk[4][2];
        #pragma unroll
        for (int tf = 0; tf < 4; ++tf) {
            float p0 = exp2_hw(st[tf][0] - m_new);
            float p1 = exp2_hw(st[tf][1] - m_new);
            float p2 = exp2_hw(st[tf][2] - m_new);
            float p3 = exp2_hw(st[tf][3] - m_new);
            ts += (p0 + p1) + (p2 + p3);
            pk[tf][0] = pack2(p0, p1);
            pk[tf][1] = pack2(p2, p3);
        }
        ts += __shfl_xor(ts, 16);
        ts += __shfl_xor(ts, 32);
        l_run = l_run * alpha + ts;
        m_run = m_new;
        #pragma unroll
        for (int af = 0; af < 4; ++af)
            #pragma unroll
            for (int r = 0; r < 4; ++r) ot[af][r] *= alpha;

        // PV: B-frag needs P[t=32kc+8g+j][li]; source reg-file granularity is 4,
        // frag granularity 8 -> gather both f candidates, select by g.
        #pragma unroll
        for (int kc = 0; kc < 2; ++kc) {
            int s1 = ((2 * g) & 3) * 16 + li;
            int s2 = ((2 * g + 1) & 3) * 16 + li;
            unsigned int w0a = (unsigned)__shfl((int)pk[2 * kc][0], s1);
            unsigned int w1a = (unsigned)__shfl((int)pk[2 * kc][1], s1);
            unsigned int w2a = (unsigned)__shfl((int)pk[2 * kc][0], s2);
            unsigned int w3a = (unsigned)__shfl((int)pk[2 * kc][1], s2);
            unsigned int w0b = (unsigned)__shfl((int)pk[2 * kc + 1][0], s1);
            unsigned int w1b = (unsigned)__shfl((int)pk[2 * kc + 1][1], s1);
            unsigned int w2b = (unsigned)__shfl((int)pk[2 * kc + 1][0], s2);
            unsigned int w3b = (unsigned)__shfl((int)pk[2 * kc + 1][1], s2);
            union { unsigned int w[4]; bf16x8 v; } pb;
            bool hi = (g >= 2);
            pb.w[0] = hi ? w0b : w0a;
            pb.w[1] = hi ? w1b : w1a;
            pb.w[2] = hi ? w2b : w2a;
            pb.w[3] = hi ? w3b : w3a;
            #pragma unroll
            for (int af = 0; af < 4; ++af) {
                bf16x8 va = *(const bf16x8*)&vt_lds[(af * 16 + li) * QPad + kc * 32 + 8 * g];
                ot[af] = __builtin_amdgcn_mfma_f32_16x16x32_bf16(va, pb.v, ot[af], 0, 0, 0);
            }
        }
    }

    float inv = 1.0f / l_run;
    #pragma unroll
    for (int af = 0; af < 4; ++af) {   // a=16af+4g+r, s=s0+16w+li -> packed 4xbf16
        uint2 u;
        u.x = pack2(ot[af][0] * inv, ot[af][1] * inv);
        u.y = pack2(ot[af][2] * inv, ot[af][3] * inv);
        *(uint2*)&attn[base + (size_t)(s0 + wid * 16 + li) * AN + af * 16 + 4 * g] = u;
    }
}

// ---------------- out = attn @ Wo, computed as out^T = WoT x attn^T-as-B
__global__ __launch_bounds__(256) void k_outproj(
    const unsigned short* __restrict__ attn, const unsigned short* __restrict__ WoT,
    float* __restrict__ out)
{
    __shared__ unsigned short a_lds[64 * QPad];
    const int tid = threadIdx.x;
    const int wid = tid >> 6, lane = tid & 63, g = lane >> 4, li = lane & 15;
    const int ob = (blockIdx.x & 3) * 64;
    const int s0 = (blockIdx.x >> 2) * 64;
    {
        int row = tid >> 2, seg = tid & 3;
        const uint4* src = (const uint4*)(attn + (size_t)(s0 + row) * AN + seg * 16);
        uint4* dst = (uint4*)&a_lds[row * QPad + seg * 16];
        dst[0] = src[0]; dst[1] = src[1];
    }
    bf16x8 wf[2];
    wf[0] = *(const bf16x8*)&WoT[(size_t)(ob + wid * 16 + li) * AN + 8 * g];
    wf[1] = *(const bf16x8*)&WoT[(size_t)(ob + wid * 16 + li) * AN + 32 + 8 * g];
    __syncthreads();
    #pragma unroll
    for (int sf = 0; sf < 4; ++sf) {
        f32x4 acc = {};
        bf16x8 b0 = *(const bf16x8*)&a_lds[(sf * 16 + li) * QPad + 8 * g];
        bf16x8 b1 = *(const bf16x8*)&a_lds[(sf * 16 + li) * QPad + 32 + 8 * g];
        acc = __builtin_amdgcn_mfma_f32_16x16x32_bf16(wf[0], b0, acc, 0, 0, 0);
        acc = __builtin_amdgcn_mfma_f32_16x16x32_bf16(wf[1], b1, acc, 0, 0, 0);
        float4 o;
        o.x = acc[0]; o.y = acc[1]; o.z = acc[2]; o.w = acc[3];
        *(float4*)&out[(size_t)(s0 + sf * 16 + li) * ON + ob + wid * 16 + 4 * g] = o;
    }
}

extern "C" void kernel_launch(void* const* d_in, const int* in_sizes, int n_in,
                              void* d_out, int out_size, void* d_ws, size_t ws_size,
                              hipStream_t stream) {
    const float* x  = (const float*)d_in[0];
    const float* Wk = (const float*)d_in[1];
    const float* Wq = (const float*)d_in[2];
    const float* Wv = (const float*)d_in[3];
    const float* Wo = (const float*)d_in[4];
    float* out = (float*)d_out;

    char* ws = (char*)d_ws;
    unsigned short* WT  = (unsigned short*)(ws);                          // 96 KB
    unsigned short* WoT = (unsigned short*)(ws + 96 * 1024);              // 32 KB
    unsigned short* Qb  = (unsigned short*)(ws + 128 * 1024);             // 2 MB
    unsigned short* Kb  = (unsigned short*)(ws + 128 * 1024 + (1u << 21));
    unsigned short* VTb = (unsigned short*)(ws + 128 * 1024 + (2u << 21));
    unsigned short* ATb = (unsigned short*)(ws + 128 * 1024 + (3u << 21));

    k_wtrans<<<4, 256, 0, stream>>>(Wk, Wq, Wv, Wo, WT, WoT);
    k_proj<<<768, 256, 0, stream>>>(x, WT, Kb, Qb, VTb);
    k_attn<<<256, 256, 0, stream>>>(Qb, Kb, VTb, ATb);
    k_outproj<<<1024, 256, 0, stream>>>(ATb, WoT, out);
}

// Round 2
// 134.955 us; speedup vs baseline: 1.3608x; 1.3608x over previous
//
#include <hip/hip_runtime.h>

// SelfAttention: B=4,S=4096,D=256,A=64,O=256, f32 in/out, bf16 MFMA compute.
// R2: flash attention with 4-way t-split (occupancy 4x), double-buffered
// prefetched staging, fused single-pass projections, fused combine+out-proj.

#define SQN 4096
#define AN 64
#define ON 256
#define QP 72      // LDS row pad: 144B stride -> 2-way bank conflict max

typedef short bf16x8 __attribute__((ext_vector_type(8)));
typedef float f32x4 __attribute__((ext_vector_type(4)));

__device__ __forceinline__ unsigned short f2bf(float f) {
    unsigned int u = __float_as_uint(f);
    u += 0x7fffu + ((u >> 16) & 1u);   // RNE
    return (unsigned short)(u >> 16);
}
__device__ __forceinline__ unsigned int pack2(float a, float b) {
    return (unsigned int)f2bf(a) | ((unsigned int)f2bf(b) << 16);
}
__device__ __forceinline__ float exp2_hw(float x) {
    float r; asm("v_exp_f32 %0, %1" : "=v"(r) : "v"(x)); return r;
}

// ---------------- weight transpose: W[d][a]->WT[(p*64+a)][d] bf16 (Wq scaled), Wo->WoT[o][a]
__global__ __launch_bounds__(256) void k_wtrans(
    const float* __restrict__ Wk, const float* __restrict__ Wq,
    const float* __restrict__ Wv, const float* __restrict__ Wo,
    unsigned short* __restrict__ WT, unsigned short* __restrict__ WoT)
{
    int bidx = blockIdx.x, tid = threadIdx.x;
    if (bidx < 24) {
        int m = bidx >> 3, chunk = bidx & 7;          // 8 a-rows per block
        const float* src = (m == 0) ? Wk : (m == 1) ? Wq : Wv;
        float scl = (m == 1) ? 0.18033688011112042f : 1.0f;  // 0.125*log2(e)
        unsigned short* dst = WT + (m * 64 + chunk * 8) * 256;
        for (int idx = tid; idx < 8 * 256; idx += 256) {
            int a = chunk * 8 + (idx >> 8), d = idx & 255;
            dst[idx] = f2bf(src[d * 64 + a] * scl);
        }
    } else {
        int chunk = bidx - 24;                        // 32 o-rows per block
        for (int idx = tid; idx < 32 * 64; idx += 256) {
            int o = chunk * 32 + (idx >> 6), a = idx & 63;
            WoT[o * 64 + a] = f2bf(Wo[a * 256 + o]);
        }
    }
}

// ---------------- fused projections: x[16384][256] -> K,Q [s][a] bf16; V -> VT[b*64+a][s]
// grid 256, block 256 (4 waves). Waves split the 192 output channels (3 x 16 each).
__global__ __launch_bounds__(256) void k_proj(
    const float* __restrict__ x, const unsigned short* __restrict__ WT,
    unsigned short* __restrict__ Ko, unsigned short* __restrict__ Qo,
    unsigned short* __restrict__ VTo)
{
    __shared__ unsigned short w_lds[192 * 128];   // 48 KB, XOR-swizzled rows
    __shared__ unsigned short x_lds[64 * 128];    // 16 KB, XOR-swizzled rows
    const int tid = threadIdx.x;
    const int wid = tid >> 6, lane = tid & 63, g = lane >> 4, li = lane & 15;
    const int s0 = blockIdx.x * 64;

    f32x4 acc[3][4] = {};
    for (int dh = 0; dh < 2; ++dh) {
        __syncthreads();
        {   // stage x half: 64 rows x 128 d, f32->bf16, swizzled
            int row = tid >> 2, seg = tid & 3;
            const float4* src = (const float4*)(x + (size_t)(s0 + row) * 256 + dh * 128 + seg * 32);
            #pragma unroll
            for (int c = 0; c < 4; ++c) {
                float4 v0 = src[2 * c], v1 = src[2 * c + 1];
                uint4 o;
                o.x = pack2(v0.x, v0.y); o.y = pack2(v0.z, v0.w);
                o.z = pack2(v1.x, v1.y); o.w = pack2(v1.z, v1.w);
                *(uint4*)((char*)x_lds + row * 256 + ((seg * 64 + c * 16) ^ ((row & 7) << 4))) = o;
            }
        }
        {   // stage W half: 192 rows x 128 d bf16, swizzled
            #pragma unroll
            for (int c = 0; c < 12; ++c) {
                int ch = tid + 256 * c;
                int row = ch >> 4, k16 = ch & 15;
                uint4 v = *(const uint4*)(WT + row * 256 + dh * 128 + k16 * 8);
                *(uint4*)((char*)w_lds + row * 256 + ((k16 * 16) ^ ((row & 7) << 4))) = v;
            }
        }
        __syncthreads();
        #pragma unroll
        for (int dc = 0; dc < 4; ++dc) {
            bf16x8 afr[4];
            #pragma unroll
            for (int sf = 0; sf < 4; ++sf) {
                int ar = sf * 16 + li;
                afr[sf] = *(const bf16x8*)((char*)x_lds + ar * 256 + ((dc * 64 + 16 * g) ^ ((ar & 7) << 4)));
            }
            #pragma unroll
            for (int c = 0; c < 3; ++c) {
                int br = (wid * 3 + c) * 16 + li;
                bf16x8 bfr = *(const bf16x8*)((char*)w_lds + br * 256 + ((dc * 64 + 16 * g) ^ ((br & 7) << 4)));
                #pragma unroll
                for (int sf = 0; sf < 4; ++sf)
                    acc[c][sf] = __builtin_amdgcn_mfma_f32_16x16x32_bf16(afr[sf], bfr, acc[c][sf], 0, 0, 0);
            }
        }
    }
    // epilogue: D[i=s-local 4g+r][j=out col li] per (c, sf)
    const int b = s0 >> 12;
    #pragma unroll
    for (int c = 0; c < 3; ++c) {
        int cfg = wid * 3 + c;            // 0..11 across waves
        int p = cfg >> 2, col = (cfg & 3) * 16 + li;
        if (p == 2) {
            int a = col;
            #pragma unroll
            for (int sf = 0; sf < 4; ++sf) {
                int sb = (s0 & 4095) + sf * 16 + 4 * g;
                uint2 u;
                u.x = pack2(acc[c][sf][0], acc[c][sf][1]);
                u.y = pack2(acc[c][sf][2], acc[c][sf][3]);
                *(uint2*)&VTo[(((size_t)(b * 64 + a)) << 12) + sb] = u;
            }
        } else {
            unsigned short* dst = (p == 0) ? Ko : Qo;
            #pragma unroll
            for (int sf = 0; sf < 4; ++sf)
                #pragma unroll
                for (int r = 0; r < 4; ++r)
                    dst[(size_t)(s0 + sf * 16 + 4 * g + r) * 64 + col] = f2bf(acc[c][sf][r]);
        }
    }
}

// ---------------- flash attention, 4-way t-split, double-buffered prefetch
// grid 1024 = b(4) x s-chunk(64) x split(4); block 256 (4 waves, 16 s-rows each).
__global__ __launch_bounds__(256) void k_attn(
    const unsigned short* __restrict__ Qg, const unsigned short* __restrict__ Kg,
    const unsigned short* __restrict__ VTg,
    float* __restrict__ Opart, float* __restrict__ Mb, float* __restrict__ Lb)
{
    __shared__ unsigned short q_lds[2][64 * QP];
    __shared__ unsigned short v_lds[2][64 * QP];
    const int tid = threadIdx.x;
    const int wid = tid >> 6, lane = tid & 63, g = lane >> 4, li = lane & 15;
    const int b = blockIdx.x >> 8;
    const int s0 = ((blockIdx.x >> 2) & 63) * 64;
    const int h = blockIdx.x & 3;
    const int t_beg = h * 1024;
    const size_t base = (size_t)b * SQN * AN;
    const int srow = tid >> 2, sseg = tid & 3;

    // K fragments directly from global (rows s = s0 + wid*16 + li)
    bf16x8 kfrag[2];
    {
        const unsigned short* kp = Kg + base + (size_t)(s0 + wid * 16 + li) * 64;
        kfrag[0] = *(const bf16x8*)(kp + 8 * g);
        kfrag[1] = *(const bf16x8*)(kp + 32 + 8 * g);
    }

    // prologue: stage tile 0 of this split
    {
        const uint4* qs = (const uint4*)(Qg + base + (size_t)(t_beg + srow) * 64 + sseg * 16);
        const uint4* vs = (const uint4*)(VTg + (((size_t)(b * 64 + srow)) << 12) + t_beg + sseg * 16);
        uint4 q0 = qs[0], q1 = qs[1], v0 = vs[0], v1 = vs[1];
        uint4* qd = (uint4*)&q_lds[0][srow * QP + sseg * 16];
        uint4* vd = (uint4*)&v_lds[0][srow * QP + sseg * 16];
        qd[0] = q0; qd[1] = q1; vd[0] = v0; vd[1] = v1;
    }
    __syncthreads();

    f32x4 ot[4] = {};
    float m_run = -1e30f, l_run = 0.0f;
    int cur = 0;

    for (int ti = 0; ti < 16; ++ti) {
        // issue next tile's global loads (overlap with compute below)
        uint4 qr0, qr1, vr0, vr1;
        const bool pf = (ti < 15);
        if (pf) {
            int t1 = t_beg + (ti + 1) * 64;
            const uint4* qs = (const uint4*)(Qg + base + (size_t)(t1 + srow) * 64 + sseg * 16);
            const uint4* vs = (const uint4*)(VTg + (((size_t)(b * 64 + srow)) << 12) + t1 + sseg * 16);
            qr0 = qs[0]; qr1 = qs[1]; vr0 = vs[0]; vr1 = vs[1];
        }

        // QK^T: S^T[t][s], lane holds t = 16tf+4g+r, s = li (within wave's 16-row group)
        f32x4 st[4];
        #pragma unroll
        for (int tf = 0; tf < 4; ++tf) {
            f32x4 a0 = {};
            bf16x8 qa0 = *(const bf16x8*)&q_lds[cur][(tf * 16 + li) * QP + 8 * g];
            bf16x8 qa1 = *(const bf16x8*)&q_lds[cur][(tf * 16 + li) * QP + 32 + 8 * g];
            a0 = __builtin_amdgcn_mfma_f32_16x16x32_bf16(qa0, kfrag[0], a0, 0, 0, 0);
            a0 = __builtin_amdgcn_mfma_f32_16x16x32_bf16(qa1, kfrag[1], a0, 0, 0, 0);
            st[tf] = a0;
        }

        // online softmax across t (in-lane 16 + xor16/32)
        float tm = -1e30f;
        #pragma unroll
        for (int tf = 0; tf < 4; ++tf)
            #pragma unroll
            for (int r = 0; r < 4; ++r) tm = fmaxf(tm, st[tf][r]);
        tm = fmaxf(tm, __shfl_xor(tm, 16));
        tm = fmaxf(tm, __shfl_xor(tm, 32));
        float m_new = fmaxf(m_run, tm);
        float alpha = exp2_hw(m_run - m_new);
        float ts = 0.0f;
        unsigned int pk[4][2];
        #pragma unroll
        for (int tf = 0; tf < 4; ++tf) {
            float p0 = exp2_hw(st[tf][0] - m_new);
            float p1 = exp2_hw(st[tf][1] - m_new);
            float p2 = exp2_hw(st[tf][2] - m_new);
            float p3 = exp2_hw(st[tf][3] - m_new);
            ts += (p0 + p1) + (p2 + p3);
            pk[tf][0] = pack2(p0, p1);
            pk[tf][1] = pack2(p2, p3);
        }
        ts += __shfl_xor(ts, 16);
        ts += __shfl_xor(ts, 32);
        l_run = l_run * alpha + ts;
        m_run = m_new;
        #pragma unroll
        for (int af = 0; af < 4; ++af)
            #pragma unroll
            for (int r = 0; r < 4; ++r) ot[af][r] *= alpha;

        // PV: gather P B-frags from 2 source lanes (reg granularity 4 vs frag 8)
        #pragma unroll
        for (int kc = 0; kc < 2; ++kc) {
            int s1 = ((2 * g) & 3) * 16 + li;
            int s2 = ((2 * g + 1) & 3) * 16 + li;
            unsigned int w0a = (unsigned)__shfl((int)pk[2 * kc][0], s1);
            unsigned int w1a = (unsigned)__shfl((int)pk[2 * kc][1], s1);
            unsigned int w2a = (unsigned)__shfl((int)pk[2 * kc][0], s2);
            unsigned int w3a = (unsigned)__shfl((int)pk[2 * kc][1], s2);
            unsigned int w0b = (unsigned)__shfl((int)pk[2 * kc + 1][0], s1);
            unsigned int w1b = (unsigned)__shfl((int)pk[2 * kc + 1][1], s1);
            unsigned int w2b = (unsigned)__shfl((int)pk[2 * kc + 1][0], s2);
            unsigned int w3b = (unsigned)__shfl((int)pk[2 * kc + 1][1], s2);
            union { unsigned int w[4]; bf16x8 v; } pb;
            bool hi = (g >= 2);
            pb.w[0] = hi ? w0b : w0a;
            pb.w[1] = hi ? w1b : w1a;
            pb.w[2] = hi ? w2b : w2a;
            pb.w[3] = hi ? w3b : w3a;
            #pragma unroll
            for (int af = 0; af < 4; ++af) {
                bf16x8 va = *(const bf16x8*)&v_lds[cur][(af * 16 + li) * QP + kc * 32 + 8 * g];
                ot[af] = __builtin_amdgcn_mfma_f32_16x16x32_bf16(va, pb.v, ot[af], 0, 0, 0);
            }
        }

        __syncthreads();               // all waves done reading buf[cur^1] (last iter) & this iter's reads of cur done for writers
        if (pf) {
            uint4* qd = (uint4*)&q_lds[cur ^ 1][srow * QP + sseg * 16];
            uint4* vd = (uint4*)&v_lds[cur ^ 1][srow * QP + sseg * 16];
            qd[0] = qr0; qd[1] = qr1; vd[0] = vr0; vd[1] = vr1;
        }
        __syncthreads();               // next buffer ready
        cur ^= 1;
    }

    // epilogue: unnormalized partial O^T (lane: a = af*16+4g+r, s = s0+wid*16+li)
    const int s = s0 + wid * 16 + li;
    float* op = Opart + ((size_t)((h * 4 + b) * 4096 + s)) * 64;
    #pragma unroll
    for (int af = 0; af < 4; ++af) {
        float4 o;
        o.x = ot[af][0]; o.y = ot[af][1]; o.z = ot[af][2]; o.w = ot[af][3];
        *(float4*)(op + af * 16 + 4 * g) = o;
    }
    if (g == 0) {
        Mb[(h * 4 + b) * 4096 + s] = m_run;
        Lb[(h * 4 + b) * 4096 + s] = l_run;
    }
}

// ---------------- combine 4 splits + out-projection, grid 256 = b(4) x s-chunk(64)
__global__ __launch_bounds__(256) void k_combine_oproj(
    const float* __restrict__ Opart, const float* __restrict__ Mb, const float* __restrict__ Lb,
    const unsigned short* __restrict__ WoT, float* __restrict__ out)
{
    __shared__ unsigned short a_lds[64 * QP];
    const int tid = threadIdx.x;
    const int b = blockIdx.x >> 6;
    const int s0 = (blockIdx.x & 63) * 64;

    {   // phase 1: merge splits -> normalized attn tile (bf16) in LDS
        int row = tid >> 2, seg = tid & 3;      // row 0..63, seg = 16-a chunk
        size_t ridx = (size_t)b * 4096 + s0 + row;
        float mm[4], ll[4];
        #pragma unroll
        for (int hh = 0; hh < 4; ++hh) { mm[hh] = Mb[hh * 16384 + ridx]; ll[hh] = Lb[hh * 16384 + ridx]; }
        float M = fmaxf(fmaxf(mm[0], mm[1]), fmaxf(mm[2], mm[3]));
        float w[4], denom = 0.0f;
        #pragma unroll
        for (int hh = 0; hh < 4; ++hh) { w[hh] = exp2_hw(mm[hh] - M); denom += w[hh] * ll[hh]; }
        float inv = 1.0f / denom;
        float av[16];
        #pragma unroll
        for (int j = 0; j < 16; ++j) av[j] = 0.0f;
        #pragma unroll
        for (int hh = 0; hh < 4; ++hh) {
            const float* op = Opart + ((size_t)hh * 16384 + ridx) * 64 + seg * 16;
            #pragma unroll
            for (int c = 0; c < 4; ++c) {
                float4 v = *(const float4*)(op + c * 4);
                av[4 * c + 0] += w[hh] * v.x; av[4 * c + 1] += w[hh] * v.y;
                av[4 * c + 2] += w[hh] * v.z; av[4 * c + 3] += w[hh] * v.w;
            }
        }
        uint4 u0, u1;
        u0.x = pack2(av[0] * inv, av[1] * inv);  u0.y = pack2(av[2] * inv, av[3] * inv);
        u0.z = pack2(av[4] * inv, av[5] * inv);  u0.w = pack2(av[6] * inv, av[7] * inv);
        u1.x = pack2(av[8] * inv, av[9] * inv);  u1.y = pack2(av[10] * inv, av[11] * inv);
        u1.z = pack2(av[12] * inv, av[13] * inv); u1.w = pack2(av[14] * inv, av[15] * inv);
        *(uint4*)&a_lds[row * QP + seg * 16] = u0;
        *(uint4*)&a_lds[row * QP + seg * 16 + 8] = u1;
    }
    __syncthreads();

    // phase 2: out[s][o] = attn @ Wo^T-frags. Wave wid owns o-range wid*64..+63.
    const int wid = tid >> 6, lane = tid & 63, g = lane >> 4, li = lane & 15;
    bf16x8 wf[4][2];
    #pragma unroll
    for (int of = 0; of < 4; ++of) {
        const unsigned short* wp = WoT + (size_t)(wid * 64 + of * 16 + li) * 64;
        wf[of][0] = *(const bf16x8*)(wp + 8 * g);
        wf[of][1] = *(const bf16x8*)(wp + 32 + 8 * g);
    }
    #pragma unroll
    for (int sf = 0; sf < 4; ++sf) {
        bf16x8 b0 = *(const bf16x8*)&a_lds[(sf * 16 + li) * QP + 8 * g];
        bf16x8 b1 = *(const bf16x8*)&a_lds[(sf * 16 + li) * QP + 32 + 8 * g];
        #pragma unroll
        for (int of = 0; of < 4; ++of) {
            f32x4 acc = {};
            acc = __builtin_amdgcn_mfma_f32_16x16x32_bf16(wf[of][0], b0, acc, 0, 0, 0);
            acc = __builtin_amdgcn_mfma_f32_16x16x32_bf16(wf[of][1], b1, acc, 0, 0, 0);
            float4 o;
            o.x = acc[0]; o.y = acc[1]; o.z = acc[2]; o.w = acc[3];
            *(float4*)&out[((size_t)b * 4096 + s0 + sf * 16 + li) * 256 + wid * 64 + of * 16 + 4 * g] = o;
        }
    }
}

extern "C" void kernel_launch(void* const* d_in, const int* in_sizes, int n_in,
                              void* d_out, int out_size, void* d_ws, size_t ws_size,
                              hipStream_t stream) {
    const float* x  = (const float*)d_in[0];
    const float* Wk = (const float*)d_in[1];
    const float* Wq = (const float*)d_in[2];
    const float* Wv = (const float*)d_in[3];
    const float* Wo = (const float*)d_in[4];
    float* out = (float*)d_out;

    char* ws = (char*)d_ws;
    unsigned short* WT  = (unsigned short*)(ws);                    // 96 KB  [192][256]
    unsigned short* WoT = (unsigned short*)(ws + 98304);            // 32 KB  [256][64]
    unsigned short* Qb  = (unsigned short*)(ws + 131072);           // 2 MB   [b*4096+s][64]
    unsigned short* Kb  = (unsigned short*)(ws + 131072 + (1u<<21));// 2 MB
    unsigned short* VTb = (unsigned short*)(ws + 131072 + (2u<<21));// 2 MB   [b*64+a][4096]
    float* Opart = (float*)(ws + 131072 + (3u<<21));                // 16 MB  [h*4+b][4096][64]
    float* Mb    = (float*)(ws + 131072 + (3u<<21) + (16u<<20));    // 256 KB [h*4+b][4096]
    float* Lb    = (float*)(ws + 131072 + (3u<<21) + (17u<<20));    // 256 KB

    k_wtrans<<<32, 256, 0, stream>>>(Wk, Wq, Wv, Wo, WT, WoT);
    k_proj<<<256, 256, 0, stream>>>(x, WT, Kb, Qb, VTb);
    k_attn<<<1024, 256, 0, stream>>>(Qb, Kb, VTb, Opart, Mb, Lb);
    k_combine_oproj<<<256, 256, 0, stream>>>(Opart, Mb, Lb, WoT, out);
}

// Round 3
// 126.684 us; speedup vs baseline: 1.4496x; 1.0653x over previous
//
#include <hip/hip_runtime.h>

// SelfAttention: B=4,S=4096,D=256,A=64,O=256, f32 in/out, bf16 MFMA compute.
// R3: k_attn: P-redistribution via same-wave LDS tile (no bpermute storm),
// cvt_pk packing, defer-max rescale skip, XOR-swizzled unpadded tiles.
// k_proj: W-frags direct from L2, 1 barrier. k_combine: grid 1024.

#define SQN 4096
#define AN 64
#define ON 256

typedef short bf16x8 __attribute__((ext_vector_type(8)));
typedef float f32x4 __attribute__((ext_vector_type(4)));

__device__ __forceinline__ unsigned short f2bf(float f) {
    unsigned int u = __float_as_uint(f);
    u += 0x7fffu + ((u >> 16) & 1u);   // RNE
    return (unsigned short)(u >> 16);
}
__device__ __forceinline__ unsigned int cvtpk(float lo, float hi) {
    unsigned int r;
    asm("v_cvt_pk_bf16_f32 %0, %1, %2" : "=v"(r) : "v"(lo), "v"(hi));
    return r;
}
__device__ __forceinline__ float exp2_hw(float x) {
    float r; asm("v_exp_f32 %0, %1" : "=v"(r) : "v"(x)); return r;
}

// ---------------- weight transpose: W[d][a]->WT[(p*64+a)][d] bf16 (Wq scaled), Wo->WoT[o][a]
__global__ __launch_bounds__(256) void k_wtrans(
    const float* __restrict__ Wk, const float* __restrict__ Wq,
    const float* __restrict__ Wv, const float* __restrict__ Wo,
    unsigned short* __restrict__ WT, unsigned short* __restrict__ WoT)
{
    int bidx = blockIdx.x, tid = threadIdx.x;
    if (bidx < 24) {
        int m = bidx >> 3, chunk = bidx & 7;          // 8 a-rows per block
        const float* src = (m == 0) ? Wk : (m == 1) ? Wq : Wv;
        float scl = (m == 1) ? 0.18033688011112042f : 1.0f;  // 0.125*log2(e)
        unsigned short* dst = WT + (m * 64 + chunk * 8) * 256;
        for (int idx = tid; idx < 8 * 256; idx += 256) {
            int a = chunk * 8 + (idx >> 8), d = idx & 255;
            dst[idx] = f2bf(src[d * 64 + a] * scl);
        }
    } else {
        int chunk = bidx - 24;                        // 32 o-rows per block
        for (int idx = tid; idx < 32 * 64; idx += 256) {
            int o = chunk * 32 + (idx >> 6), a = idx & 63;
            WoT[o * 64 + a] = f2bf(Wo[a * 256 + o]);
        }
    }
}

// ---------------- fused projections: x -> K,Q [s][a] bf16; V -> VT[b*64+a][s]
// grid 512 (32-row s-tiles), block 256. W B-frags read directly from global (L2).
__global__ __launch_bounds__(256) void k_proj(
    const float* __restrict__ x, const unsigned short* __restrict__ WT,
    unsigned short* __restrict__ Ko, unsigned short* __restrict__ Qo,
    unsigned short* __restrict__ VTo)
{
    __shared__ unsigned short x_lds[32 * 256];    // 16 KB, 16B-unit XOR swizzle
    const int tid = threadIdx.x;
    const int wid = tid >> 6, lane = tid & 63, g = lane >> 4, li = lane & 15;
    const int s0 = blockIdx.x * 32;

    {   // stage x tile: fully-coalesced float4 reads, cvt_pk to bf16, swizzled write
        const float4* xs = (const float4*)(x + (size_t)s0 * 256);
        #pragma unroll
        for (int i = 0; i < 8; ++i) {
            int idx4 = i * 256 + tid;
            float4 v = xs[idx4];
            int row = idx4 >> 6, q = idx4 & 63;
            int unit = q >> 1, half = q & 1;
            uint2 u; u.x = cvtpk(v.x, v.y); u.y = cvtpk(v.z, v.w);
            *(uint2*)&x_lds[row * 256 + ((unit ^ (row & 7)) << 3) + half * 4] = u;
        }
    }
    __syncthreads();

    f32x4 acc[3][2] = {};
    #pragma unroll
    for (int dc = 0; dc < 8; ++dc) {
        bf16x8 afr[2];
        #pragma unroll
        for (int sf = 0; sf < 2; ++sf) {
            int ar = sf * 16 + li;
            afr[sf] = *(const bf16x8*)&x_lds[ar * 256 + (((4 * dc + g) ^ (ar & 7)) << 3)];
        }
        #pragma unroll
        for (int c = 0; c < 3; ++c) {
            int wc = (wid * 3 + c) * 16 + li;
            bf16x8 bfr = *(const bf16x8*)&WT[wc * 256 + dc * 32 + 8 * g];
            #pragma unroll
            for (int sf = 0; sf < 2; ++sf)
                acc[c][sf] = __builtin_amdgcn_mfma_f32_16x16x32_bf16(afr[sf], bfr, acc[c][sf], 0, 0, 0);
        }
    }

    const int b = s0 >> 12;
    #pragma unroll
    for (int c = 0; c < 3; ++c) {
        int cfg = wid * 3 + c;                // 0..11
        int p = cfg >> 2, col = (cfg & 3) * 16 + li;
        if (p == 2) {
            #pragma unroll
            for (int sf = 0; sf < 2; ++sf) {
                int sb = (s0 & 4095) + sf * 16 + 4 * g;
                uint2 u;
                u.x = cvtpk(acc[c][sf][0], acc[c][sf][1]);
                u.y = cvtpk(acc[c][sf][2], acc[c][sf][3]);
                *(uint2*)&VTo[(((size_t)(b * 64 + col)) << 12) + sb] = u;
            }
        } else {
            unsigned short* dst = (p == 0) ? Ko : Qo;
            #pragma unroll
            for (int sf = 0; sf < 2; ++sf)
                #pragma unroll
                for (int r = 0; r < 4; ++r)
                    dst[(size_t)(s0 + sf * 16 + 4 * g + r) * 64 + col] = f2bf(acc[c][sf][r]);
        }
    }
}

// ---------------- flash attention, 4-way t-split, dbuf prefetch, LDS P-tile
// grid 1024 = b(4) x s-chunk(64) x split(4); block 256 (4 waves, 16 s-rows each).
__global__ __launch_bounds__(256) void k_attn(
    const unsigned short* __restrict__ Qg, const unsigned short* __restrict__ Kg,
    const unsigned short* __restrict__ VTg,
    float* __restrict__ Opart, float* __restrict__ Mb, float* __restrict__ Lb)
{
    __shared__ unsigned short q_lds[2][64 * 64];   // [t][a], swizzled, 8KB each
    __shared__ unsigned short v_lds[2][64 * 64];   // [a][t], swizzled
    __shared__ unsigned int   p_lds[4][16 * 32];   // per-wave P tile [s=li][tpair], swizzled
    const int tid = threadIdx.x;
    const int wid = tid >> 6, lane = tid & 63, g = lane >> 4, li = lane & 15;
    const int b = blockIdx.x >> 8;
    const int s0 = ((blockIdx.x >> 2) & 63) * 64;
    const int h = blockIdx.x & 3;
    const int t_beg = h * 1024;
    const size_t base = (size_t)b * SQN * AN;
    const int srow = tid >> 2, sseg = tid & 3, r7 = srow & 7;
    const int l7 = li & 7;

    // K fragments directly from global (rows s = s0 + wid*16 + li)
    bf16x8 kfrag[2];
    {
        const unsigned short* kp = Kg + base + (size_t)(s0 + wid * 16 + li) * 64;
        kfrag[0] = *(const bf16x8*)(kp + 8 * g);
        kfrag[1] = *(const bf16x8*)(kp + 32 + 8 * g);
    }

    {   // prologue: stage tile 0
        const uint4* qs = (const uint4*)(Qg + base + (size_t)(t_beg + srow) * 64 + sseg * 16);
        const uint4* vs = (const uint4*)(VTg + (((size_t)(b * 64 + srow)) << 12) + t_beg + sseg * 16);
        uint4 q0 = qs[0], q1 = qs[1], v0 = vs[0], v1 = vs[1];
        *(uint4*)&q_lds[0][srow * 64 + (((2 * sseg) ^ r7) << 3)] = q0;
        *(uint4*)&q_lds[0][srow * 64 + (((2 * sseg + 1) ^ r7) << 3)] = q1;
        *(uint4*)&v_lds[0][srow * 64 + (((2 * sseg) ^ r7) << 3)] = v0;
        *(uint4*)&v_lds[0][srow * 64 + (((2 * sseg + 1) ^ r7) << 3)] = v1;
    }
    __syncthreads();

    f32x4 ot[4] = {};
    float m_run = -1e30f, l_run = 0.0f;
    int cur = 0;

    for (int ti = 0; ti < 16; ++ti) {
        // issue next tile's global loads (hide under compute)
        uint4 qr0, qr1, vr0, vr1;
        const bool pf = (ti < 15);
        if (pf) {
            int t1 = t_beg + (ti + 1) * 64;
            const uint4* qs = (const uint4*)(Qg + base + (size_t)(t1 + srow) * 64 + sseg * 16);
            const uint4* vs = (const uint4*)(VTg + (((size_t)(b * 64 + srow)) << 12) + t1 + sseg * 16);
            qr0 = qs[0]; qr1 = qs[1]; vr0 = vs[0]; vr1 = vs[1];
        }

        // QK^T: S^T[t][s], lane holds t = 16tf+4g+r, s = li
        f32x4 st[4];
        #pragma unroll
        for (int tf = 0; tf < 4; ++tf) {
            f32x4 a0 = {};
            int qr = tf * 16 + li;
            bf16x8 qa0 = *(const bf16x8*)&q_lds[cur][qr * 64 + ((g ^ l7) << 3)];
            bf16x8 qa1 = *(const bf16x8*)&q_lds[cur][qr * 64 + (((4 + g) ^ l7) << 3)];
            a0 = __builtin_amdgcn_mfma_f32_16x16x32_bf16(qa0, kfrag[0], a0, 0, 0, 0);
            a0 = __builtin_amdgcn_mfma_f32_16x16x32_bf16(qa1, kfrag[1], a0, 0, 0, 0);
            st[tf] = a0;
        }

        // online softmax with defer-max (THR=8 in log2 domain)
        float tm = -1e30f;
        #pragma unroll
        for (int tf = 0; tf < 4; ++tf)
            #pragma unroll
            for (int r = 0; r < 4; ++r) tm = fmaxf(tm, st[tf][r]);
        tm = fmaxf(tm, __shfl_xor(tm, 16));
        tm = fmaxf(tm, __shfl_xor(tm, 32));
        if (__any(tm > m_run + 8.0f)) {
            float m_new = fmaxf(m_run, tm);
            float alpha = exp2_hw(m_run - m_new);
            #pragma unroll
            for (int af = 0; af < 4; ++af)
                #pragma unroll
                for (int r = 0; r < 4; ++r) ot[af][r] *= alpha;
            l_run *= alpha;
            m_run = m_new;
        }
        float ts = 0.0f;
        #pragma unroll
        for (int tf = 0; tf < 4; ++tf) {
            float p0 = exp2_hw(st[tf][0] - m_run);
            float p1 = exp2_hw(st[tf][1] - m_run);
            float p2 = exp2_hw(st[tf][2] - m_run);
            float p3 = exp2_hw(st[tf][3] - m_run);
            ts += (p0 + p1) + (p2 + p3);
            uint2 u; u.x = cvtpk(p0, p1); u.y = cvtpk(p2, p3);
            // P tile: word wi holds t-pair (2wi, 2wi+1) at s-row li; XOR swizzle bits 2-4
            int wi = 8 * tf + 2 * g;
            *(uint2*)&p_lds[wid][li * 32 + (wi ^ (l7 << 2))] = u;
        }
        ts += __shfl_xor(ts, 16);
        ts += __shfl_xor(ts, 32);
        l_run += ts;

        // PV: B-frag = words 16kc+4g..+3 of own wave's P tile (same li column)
        #pragma unroll
        for (int kc = 0; kc < 2; ++kc) {
            uint4 pw = *(const uint4*)&p_lds[wid][li * 32 + ((16 * kc + 4 * g) ^ (l7 << 2))];
            union { uint4 u; bf16x8 v; } pb; pb.u = pw;
            #pragma unroll
            for (int af = 0; af < 4; ++af) {
                int vr = af * 16 + li;
                bf16x8 va = *(const bf16x8*)&v_lds[cur][vr * 64 + (((4 * kc + g) ^ (vr & 7)) << 3)];
                ot[af] = __builtin_amdgcn_mfma_f32_16x16x32_bf16(va, pb.v, ot[af], 0, 0, 0);
            }
        }

        __syncthreads();
        if (pf) {
            *(uint4*)&q_lds[cur ^ 1][srow * 64 + (((2 * sseg) ^ r7) << 3)] = qr0;
            *(uint4*)&q_lds[cur ^ 1][srow * 64 + (((2 * sseg + 1) ^ r7) << 3)] = qr1;
            *(uint4*)&v_lds[cur ^ 1][srow * 64 + (((2 * sseg) ^ r7) << 3)] = vr0;
            *(uint4*)&v_lds[cur ^ 1][srow * 64 + (((2 * sseg + 1) ^ r7) << 3)] = vr1;
        }
        __syncthreads();
        cur ^= 1;
    }

    // epilogue: unnormalized partial O^T (lane: a = af*16+4g+r, s = s0+wid*16+li)
    const int s = s0 + wid * 16 + li;
    float* op = Opart + ((size_t)((h * 4 + b) * 4096 + s)) * 64;
    #pragma unroll
    for (int af = 0; af < 4; ++af) {
        float4 o;
        o.x = ot[af][0]; o.y = ot[af][1]; o.z = ot[af][2]; o.w = ot[af][3];
        *(float4*)(op + af * 16 + 4 * g) = o;
    }
    if (g == 0) {
        Mb[(h * 4 + b) * 4096 + s] = m_run;
        Lb[(h * 4 + b) * 4096 + s] = l_run;
    }
}

// ---------------- combine 4 splits + out-projection, grid 1024 = b(4) x s-chunk(256 of 16)
__global__ __launch_bounds__(256) void k_combine_oproj(
    const float* __restrict__ Opart, const float* __restrict__ Mb, const float* __restrict__ Lb,
    const unsigned short* __restrict__ WoT, float* __restrict__ out)
{
    __shared__ unsigned short a_lds[16 * 64];      // [s][a], swizzled, 2KB
    const int tid = threadIdx.x;
    const int b = blockIdx.x >> 8;
    const int s0 = (blockIdx.x & 255) * 16;

    {   // phase 1: merge splits -> normalized attn tile (bf16) in LDS
        int row = tid >> 4, ac = (tid & 15) * 4;
        size_t ridx = (size_t)b * 4096 + s0 + row;
        float mm[4], ll[4];
        #pragma unroll
        for (int hh = 0; hh < 4; ++hh) { mm[hh] = Mb[hh * 16384 + ridx]; ll[hh] = Lb[hh * 16384 + ridx]; }
        float M = fmaxf(fmaxf(mm[0], mm[1]), fmaxf(mm[2], mm[3]));
        float w[4], denom = 0.0f;
        #pragma unroll
        for (int hh = 0; hh < 4; ++hh) { w[hh] = exp2_hw(mm[hh] - M); denom += w[hh] * ll[hh]; }
        float inv = 1.0f / denom;
        float4 av = {0.f, 0.f, 0.f, 0.f};
        #pragma unroll
        for (int hh = 0; hh < 4; ++hh) {
            float4 v = *(const float4*)&Opart[((size_t)hh * 16384 + ridx) * 64 + ac];
            av.x += w[hh] * v.x; av.y += w[hh] * v.y; av.z += w[hh] * v.z; av.w += w[hh] * v.w;
        }
        int unit = ac >> 3;
        uint2 u; u.x = cvtpk(av.x * inv, av.y * inv); u.y = cvtpk(av.z * inv, av.w * inv);
        *(uint2*)&a_lds[row * 64 + ((unit ^ (row & 7)) << 3) + (ac & 7)] = u;
    }
    __syncthreads();

    // phase 2: out[s][o]. Wave wid owns o-range wid*64..+63.
    const int wid = tid >> 6, lane = tid & 63, g = lane >> 4, li = lane & 15;
    bf16x8 b0 = *(const bf16x8*)&a_lds[li * 64 + ((g ^ (li & 7)) << 3)];
    bf16x8 b1 = *(const bf16x8*)&a_lds[li * 64 + (((4 + g) ^ (li & 7)) << 3)];
    #pragma unroll
    for (int of = 0; of < 4; ++of) {
        const unsigned short* wp = WoT + (size_t)(wid * 64 + of * 16 + li) * 64;
        bf16x8 w0 = *(const bf16x8*)(wp + 8 * g);
        bf16x8 w1 = *(const bf16x8*)(wp + 32 + 8 * g);
        f32x4 acc = {};
        acc = __builtin_amdgcn_mfma_f32_16x16x32_bf16(w0, b0, acc, 0, 0, 0);
        acc = __builtin_amdgcn_mfma_f32_16x16x32_bf16(w1, b1, acc, 0, 0, 0);
        float4 o;
        o.x = acc[0]; o.y = acc[1]; o.z = acc[2]; o.w = acc[3];
        *(float4*)&out[((size_t)b * 4096 + s0 + li) * 256 + wid * 64 + of * 16 + 4 * g] = o;
    }
}

extern "C" void kernel_launch(void* const* d_in, const int* in_sizes, int n_in,
                              void* d_out, int out_size, void* d_ws, size_t ws_size,
                              hipStream_t stream) {
    const float* x  = (const float*)d_in[0];
    const float* Wk = (const float*)d_in[1];
    const float* Wq = (const float*)d_in[2];
    const float* Wv = (const float*)d_in[3];
    const float* Wo = (const float*)d_in[4];
    float* out = (float*)d_out;

    char* ws = (char*)d_ws;
    unsigned short* WT  = (unsigned short*)(ws);                    // 96 KB  [192][256]
    unsigned short* WoT = (unsigned short*)(ws + 98304);            // 32 KB  [256][64]
    unsigned short* Qb  = (unsigned short*)(ws + 131072);           // 2 MB   [b*4096+s][64]
    unsigned short* Kb  = (unsigned short*)(ws + 131072 + (1u<<21));// 2 MB
    unsigned short* VTb = (unsigned short*)(ws + 131072 + (2u<<21));// 2 MB   [b*64+a][4096]
    float* Opart = (float*)(ws + 131072 + (3u<<21));                // 16 MB  [h*4+b][4096][64]
    float* Mb    = (float*)(ws + 131072 + (3u<<21) + (16u<<20));    // 256 KB [h*4+b][4096]
    float* Lb    = (float*)(ws + 131072 + (3u<<21) + (17u<<20));    // 256 KB

    k_wtrans<<<32, 256, 0, stream>>>(Wk, Wq, Wv, Wo, WT, WoT);
    k_proj<<<512, 256, 0, stream>>>(x, WT, Kb, Qb, VTb);
    k_attn<<<1024, 256, 0, stream>>>(Qb, Kb, VTb, Opart, Mb, Lb);
    k_combine_oproj<<<1024, 256, 0, stream>>>(Opart, Mb, Lb, WoT, out);
}

// Round 6
// 122.376 us; speedup vs baseline: 1.5007x; 1.0352x over previous
//
#include <hip/hip_runtime.h>

// SelfAttention: B=4,S=4096,D=256,A=64,O=256, f32 in/out, bf16 MFMA compute.
// R4 (2nd resubmit; R4/R5 benches lost to GPU-acquisition timeouts): single
// fused attention kernel (flash + in-LDS split-combine + out-proj), 4
// t-groups x 4 waves per 1024-thread block, quad-buffered staging with
// write-early 1-barrier schedule, depth-2 register prefetch pipeline.

#define SQN 4096
#define AN 64

typedef short bf16x8 __attribute__((ext_vector_type(8)));
typedef float f32x4 __attribute__((ext_vector_type(4)));

__device__ __forceinline__ unsigned short f2bf(float f) {
    unsigned int u = __float_as_uint(f);
    u += 0x7fffu + ((u >> 16) & 1u);   // RNE
    return (unsigned short)(u >> 16);
}
__device__ __forceinline__ unsigned int cvtpk(float lo, float hi) {
    unsigned int r;
    asm("v_cvt_pk_bf16_f32 %0, %1, %2" : "=v"(r) : "v"(lo), "v"(hi));
    return r;
}
__device__ __forceinline__ float exp2_hw(float x) {
    float r; asm("v_exp_f32 %0, %1" : "=v"(r) : "v"(x)); return r;
}

// ---------------- weight transpose: W[d][a]->WT[(p*64+a)][d] bf16 (Wq scaled), Wo->WoT[o][a]
__global__ __launch_bounds__(256) void k_wtrans(
    const float* __restrict__ Wk, const float* __restrict__ Wq,
    const float* __restrict__ Wv, const float* __restrict__ Wo,
    unsigned short* __restrict__ WT, unsigned short* __restrict__ WoT)
{
    int bidx = blockIdx.x, tid = threadIdx.x;
    if (bidx < 24) {
        int m = bidx >> 3, chunk = bidx & 7;          // 8 a-rows per block
        const float* src = (m == 0) ? Wk : (m == 1) ? Wq : Wv;
        float scl = (m == 1) ? 0.18033688011112042f : 1.0f;  // 0.125*log2(e)
        unsigned short* dst = WT + (m * 64 + chunk * 8) * 256;
        for (int idx = tid; idx < 8 * 256; idx += 256) {
            int a = chunk * 8 + (idx >> 8), d = idx & 255;
            dst[idx] = f2bf(src[d * 64 + a] * scl);
        }
    } else {
        int chunk = bidx - 24;                        // 32 o-rows per block
        for (int idx = tid; idx < 32 * 64; idx += 256) {
            int o = chunk * 32 + (idx >> 6), a = idx & 63;
            WoT[o * 64 + a] = f2bf(Wo[a * 256 + o]);
        }
    }
}

// ---------------- fused projections: x -> K,Q [s][a] bf16; V -> VT[b*64+a][s]
// grid 512 (32-row s-tiles), block 256. W B-frags read directly from global (L2).
__global__ __launch_bounds__(256) void k_proj(
    const float* __restrict__ x, const unsigned short* __restrict__ WT,
    unsigned short* __restrict__ Ko, unsigned short* __restrict__ Qo,
    unsigned short* __restrict__ VTo)
{
    __shared__ unsigned short x_lds[32 * 256];    // 16 KB, 16B-unit XOR swizzle
    const int tid = threadIdx.x;
    const int wid = tid >> 6, lane = tid & 63, g = lane >> 4, li = lane & 15;
    const int s0 = blockIdx.x * 32;

    {   // stage x tile: fully-coalesced float4 reads, cvt_pk to bf16, swizzled write
        const float4* xs = (const float4*)(x + (size_t)s0 * 256);
        #pragma unroll
        for (int i = 0; i < 8; ++i) {
            int idx4 = i * 256 + tid;
            float4 v = xs[idx4];
            int row = idx4 >> 6, q = idx4 & 63;
            int unit = q >> 1, half = q & 1;
            uint2 u; u.x = cvtpk(v.x, v.y); u.y = cvtpk(v.z, v.w);
            *(uint2*)&x_lds[row * 256 + ((unit ^ (row & 7)) << 3) + half * 4] = u;
        }
    }
    __syncthreads();

    f32x4 acc[3][2] = {};
    #pragma unroll
    for (int dc = 0; dc < 8; ++dc) {
        bf16x8 afr[2];
        #pragma unroll
        for (int sf = 0; sf < 2; ++sf) {
            int ar = sf * 16 + li;
            afr[sf] = *(const bf16x8*)&x_lds[ar * 256 + (((4 * dc + g) ^ (ar & 7)) << 3)];
        }
        #pragma unroll
        for (int c = 0; c < 3; ++c) {
            int wc = (wid * 3 + c) * 16 + li;
            bf16x8 bfr = *(const bf16x8*)&WT[wc * 256 + dc * 32 + 8 * g];
            #pragma unroll
            for (int sf = 0; sf < 2; ++sf)
                acc[c][sf] = __builtin_amdgcn_mfma_f32_16x16x32_bf16(afr[sf], bfr, acc[c][sf], 0, 0, 0);
        }
    }

    const int b = s0 >> 12;
    #pragma unroll
    for (int c = 0; c < 3; ++c) {
        int cfg = wid * 3 + c;                // 0..11
        int p = cfg >> 2, col = (cfg & 3) * 16 + li;
        if (p == 2) {
            #pragma unroll
            for (int sf = 0; sf < 2; ++sf) {
                int sb = (s0 & 4095) + sf * 16 + 4 * g;
                uint2 u;
                u.x = cvtpk(acc[c][sf][0], acc[c][sf][1]);
                u.y = cvtpk(acc[c][sf][2], acc[c][sf][3]);
                *(uint2*)&VTo[(((size_t)(b * 64 + col)) << 12) + sb] = u;
            }
        } else {
            unsigned short* dst = (p == 0) ? Ko : Qo;
            #pragma unroll
            for (int sf = 0; sf < 2; ++sf)
                #pragma unroll
                for (int r = 0; r < 4; ++r)
                    dst[(size_t)(s0 + sf * 16 + 4 * g + r) * 64 + col] = f2bf(acc[c][sf][r]);
        }
    }
}

// ---------------- fused flash attention + split-combine + out-projection
// grid 256 = b(4) x s-chunk(64 rows); block 1024 = 16 waves = 4 t-groups x 4 waves.
// Group h processes t in [h*1024, (h+1)*1024), 32 tiles of 32.
// Quad-buffered staging, write-early schedule: write(i+1); issue(i+2); barrier; compute(i).
__global__ __launch_bounds__(1024, 4) void k_attn(
    const unsigned short* __restrict__ Qg, const unsigned short* __restrict__ Kg,
    const unsigned short* __restrict__ VTg, const unsigned short* __restrict__ WoT,
    float* __restrict__ out)
{
    __shared__ unsigned short q_lds[4][4][2048];  // [grp][buf][t32][a64] swizzled, 64 KB
    __shared__ unsigned short v_lds[4][4][2048];  // [grp][buf][a64][t32] swizzled, 64 KB
    __shared__ unsigned int   p_lds[16][256];     // per-wave P tile [s16][tpair16], 16 KB

    const int tid = threadIdx.x;
    const int wid = tid >> 6, lane = tid & 63, g = lane >> 4, li = lane & 15;
    const int grp = wid >> 2, ws = wid & 3;
    const int b = blockIdx.x >> 6;
    const int s0 = (blockIdx.x & 63) * 64;
    const int t_beg = grp * 1024;
    const size_t base = (size_t)b * SQN * AN;

    // staging thread mapping (per 256-thread group)
    const int gtid = tid & 255;
    const int qrow = gtid >> 3, qseg = gtid & 7;
    const int vrow = gtid >> 2, vseg = gtid & 3;
    const int q_woff = qrow * 64 + ((qseg ^ (qrow & 7)) << 3);
    const int v_woff = vrow * 32 + (((vseg + ((vrow >> 1) & 3)) & 3) << 3);
    const unsigned short* qg0 = Qg + base + (size_t)(t_beg + qrow) * 64 + qseg * 8;
    const unsigned short* vg0 = VTg + (((size_t)(b * 64 + vrow)) << 12) + t_beg + vseg * 8;

    // K fragments (rows s = s0 + ws*16 + li) straight from global
    bf16x8 kfrag[2];
    {
        const unsigned short* kp = Kg + base + (size_t)(s0 + ws * 16 + li) * 64;
        kfrag[0] = *(const bf16x8*)(kp + 8 * g);
        kfrag[1] = *(const bf16x8*)(kp + 32 + 8 * g);
    }

    f32x4 ot[4] = {};
    float m_run = -1e30f, l_run = 0.0f;

    // prologue: tile0 -> buf0, tile1 -> regset A
    {
        uint4 q0 = *(const uint4*)(qg0);
        uint4 v0 = *(const uint4*)(vg0);
        *(uint4*)&q_lds[grp][0][q_woff] = q0;
        *(uint4*)&v_lds[grp][0][v_woff] = v0;
    }
    uint4 qsA = *(const uint4*)(qg0 + 2048);
    uint4 vsA = *(const uint4*)(vg0 + 32);
    uint4 qsB = {}, vsB = {};

    auto compute = [&](int i) {
        const unsigned short* qb = &q_lds[grp][i & 3][0];
        const unsigned short* vb = &v_lds[grp][i & 3][0];
        f32x4 st[2];
        #pragma unroll
        for (int tf = 0; tf < 2; ++tf) {
            int row = tf * 16 + li;
            bf16x8 qa0 = *(const bf16x8*)&qb[row * 64 + ((g ^ (row & 7)) << 3)];
            bf16x8 qa1 = *(const bf16x8*)&qb[row * 64 + (((4 + g) ^ (row & 7)) << 3)];
            f32x4 a0 = {};
            a0 = __builtin_amdgcn_mfma_f32_16x16x32_bf16(qa0, kfrag[0], a0, 0, 0, 0);
            a0 = __builtin_amdgcn_mfma_f32_16x16x32_bf16(qa1, kfrag[1], a0, 0, 0, 0);
            st[tf] = a0;
        }
        // online softmax over t for row s=li, defer-max THR=8 (log2 domain)
        float tm = fmaxf(fmaxf(fmaxf(st[0][0], st[0][1]), fmaxf(st[0][2], st[0][3])),
                         fmaxf(fmaxf(st[1][0], st[1][1]), fmaxf(st[1][2], st[1][3])));
        tm = fmaxf(tm, __shfl_xor(tm, 16));
        tm = fmaxf(tm, __shfl_xor(tm, 32));
        if (__any(tm > m_run + 8.0f)) {
            float m_new = fmaxf(m_run, tm);
            float alpha = exp2_hw(m_run - m_new);
            #pragma unroll
            for (int af = 0; af < 4; ++af) {
                ot[af][0] *= alpha; ot[af][1] *= alpha;
                ot[af][2] *= alpha; ot[af][3] *= alpha;
            }
            l_run *= alpha;
            m_run = m_new;
        }
        float ts = 0.0f;
        #pragma unroll
        for (int tf = 0; tf < 2; ++tf) {
            float p0 = exp2_hw(st[tf][0] - m_run);
            float p1 = exp2_hw(st[tf][1] - m_run);
            float p2 = exp2_hw(st[tf][2] - m_run);
            float p3 = exp2_hw(st[tf][3] - m_run);
            ts += (p0 + p1) + (p2 + p3);
            uint2 u; u.x = cvtpk(p0, p1); u.y = cvtpk(p2, p3);
            int w0 = 8 * tf + 2 * g;
            int su = ((w0 >> 2) + ((li >> 1) & 3)) & 3;
            *(uint2*)&p_lds[wid][li * 16 + (su << 2) + (w0 & 3)] = u;
        }
        ts += __shfl_xor(ts, 16);
        ts += __shfl_xor(ts, 32);
        l_run += ts;
        // PV: B-frag = logical words 4g..4g+3 of own wave's P row li (swizzled)
        union { uint4 u4; bf16x8 v; } pb;
        pb.u4 = *(const uint4*)&p_lds[wid][li * 16 + (((g + ((li >> 1) & 3)) & 3) << 2)];
        #pragma unroll
        for (int af = 0; af < 4; ++af) {
            int row = af * 16 + li;
            bf16x8 va = *(const bf16x8*)&vb[row * 32 + (((g + ((row >> 1) & 3)) & 3) << 3)];
            ot[af] = __builtin_amdgcn_mfma_f32_16x16x32_bf16(va, pb.v, ot[af], 0, 0, 0);
        }
    };

    for (int i = 0; i < 32; i += 2) {
        // even sub-iter i: write tile i+1 (set A); issue tile i+2 (set B)
        {
            *(uint4*)&q_lds[grp][(i + 1) & 3][q_woff] = qsA;
            *(uint4*)&v_lds[grp][(i + 1) & 3][v_woff] = vsA;
            if (i < 30) {
                qsB = *(const uint4*)(qg0 + (size_t)(i + 2) * 2048);
                vsB = *(const uint4*)(vg0 + (i + 2) * 32);
            }
            __syncthreads();
            compute(i);
        }
        // odd sub-iter i+1: write tile i+2 (set B); issue tile i+3 (set A)
        {
            if (i + 1 < 31) {
                *(uint4*)&q_lds[grp][(i + 2) & 3][q_woff] = qsB;
                *(uint4*)&v_lds[grp][(i + 2) & 3][v_woff] = vsB;
            }
            if (i + 1 < 30) {
                qsA = *(const uint4*)(qg0 + (size_t)(i + 3) * 2048);
                vsA = *(const uint4*)(vg0 + (i + 3) * 32);
            }
            __syncthreads();
            compute(i + 1);
        }
    }

    // ---------------- epilogue: in-LDS split combine + out-projection
    __syncthreads();
    float* o_part = (float*)&q_lds[0][0][0];          // 64 KB  [h][s64][a64] swizzled
    float* ml = (float*)&p_lds[0][0];                 // 2 KB   [m|l][h][s]
    unsigned short* a_lds = (unsigned short*)(ml + 512); // 8 KB [s64][a64] swizzled

    {   // write unnormalized partials (a = af*16+4g+r, s = s0+ws*16+li)
        int s_loc = ws * 16 + li;
        float* op = o_part + (size_t)(grp * 64 + s_loc) * 64;
        #pragma unroll
        for (int af = 0; af < 4; ++af) {
            int lu = 4 * af + g;
            float4 o;
            o.x = ot[af][0]; o.y = ot[af][1]; o.z = ot[af][2]; o.w = ot[af][3];
            *(float4*)(op + ((lu ^ (s_loc & 7)) << 2)) = o;
        }
        if (g == 0) {
            ml[grp * 64 + s_loc] = m_run;
            ml[256 + grp * 64 + s_loc] = l_run;
        }
    }
    __syncthreads();

    {   // combine 4 t-splits -> normalized bf16 attn tile in a_lds
        int row = tid >> 4, ac = (tid & 15) * 4;
        float mm[4], ll[4];
        #pragma unroll
        for (int h = 0; h < 4; ++h) {
            mm[h] = ml[h * 64 + row];
            ll[h] = ml[256 + h * 64 + row];
        }
        float M = fmaxf(fmaxf(mm[0], mm[1]), fmaxf(mm[2], mm[3]));
        float w[4], denom = 0.0f;
        #pragma unroll
        for (int h = 0; h < 4; ++h) { w[h] = exp2_hw(mm[h] - M); denom += w[h] * ll[h]; }
        float inv = 1.0f / denom;
        float4 av = {0.f, 0.f, 0.f, 0.f};
        #pragma unroll
        for (int h = 0; h < 4; ++h) {
            float4 v = *(const float4*)&o_part[(size_t)(h * 64 + row) * 64 + (((ac >> 2) ^ (row & 7)) << 2)];
            av.x += w[h] * v.x; av.y += w[h] * v.y; av.z += w[h] * v.z; av.w += w[h] * v.w;
        }
        int unit = ac >> 3;
        uint2 u; u.x = cvtpk(av.x * inv, av.y * inv); u.y = cvtpk(av.z * inv, av.w * inv);
        *(uint2*)&a_lds[row * 64 + ((unit ^ (row & 7)) << 3) + (ac & 7)] = u;
    }
    __syncthreads();

    {   // out[s][o] = attn @ Wo; wave = (s-quarter grp, o-quarter ws)
        int row = grp * 16 + li;
        bf16x8 b0 = *(const bf16x8*)&a_lds[row * 64 + ((g ^ (row & 7)) << 3)];
        bf16x8 b1 = *(const bf16x8*)&a_lds[row * 64 + (((4 + g) ^ (row & 7)) << 3)];
        #pragma unroll
        for (int of = 0; of < 4; ++of) {
            const unsigned short* wp = WoT + (size_t)(ws * 64 + of * 16 + li) * 64;
            bf16x8 w0 = *(const bf16x8*)(wp + 8 * g);
            bf16x8 w1 = *(const bf16x8*)(wp + 32 + 8 * g);
            f32x4 acc = {};
            acc = __builtin_amdgcn_mfma_f32_16x16x32_bf16(w0, b0, acc, 0, 0, 0);
            acc = __builtin_amdgcn_mfma_f32_16x16x32_bf16(w1, b1, acc, 0, 0, 0);
            float4 o;
            o.x = acc[0]; o.y = acc[1]; o.z = acc[2]; o.w = acc[3];
            *(float4*)&out[((size_t)b * 4096 + s0 + grp * 16 + li) * 256 + ws * 64 + of * 16 + 4 * g] = o;
        }
    }
}

extern "C" void kernel_launch(void* const* d_in, const int* in_sizes, int n_in,
                              void* d_out, int out_size, void* d_ws, size_t ws_size,
                              hipStream_t stream) {
    const float* x  = (const float*)d_in[0];
    const float* Wk = (const float*)d_in[1];
    const float* Wq = (const float*)d_in[2];
    const float* Wv = (const float*)d_in[3];
    const float* Wo = (const float*)d_in[4];
    float* out = (float*)d_out;

    char* ws = (char*)d_ws;
    unsigned short* WT  = (unsigned short*)(ws);                    // 96 KB  [192][256]
    unsigned short* WoT = (unsigned short*)(ws + 98304);            // 32 KB  [256][64]
    unsigned short* Qb  = (unsigned short*)(ws + 131072);           // 2 MB   [b*4096+s][64]
    unsigned short* Kb  = (unsigned short*)(ws + 131072 + (1u<<21));// 2 MB
    unsigned short* VTb = (unsigned short*)(ws + 131072 + (2u<<21));// 2 MB   [b*64+a][4096]

    k_wtrans<<<32, 256, 0, stream>>>(Wk, Wq, Wv, Wo, WT, WoT);
    k_proj<<<512, 256, 0, stream>>>(x, WT, Kb, Qb, VTb);
    k_attn<<<256, 1024, 0, stream>>>(Qb, Kb, VTb, WoT, out);
}